// Round 19
// baseline (30.550 us; speedup 1.0000x reference)
//
#include <hip/hip_runtime.h>
#include <math.h>

#define B_  8
#define L_  4096
#define C_  256
#define TL  32
#define WSTR 13   // padded per-task float stride in s_w (gcd(13,32)=1)

// ---- DPP wave-sum on the VALU pipe (verified R7/R9/R11) ----
template<int CTRL, int RM>
__device__ __forceinline__ float dpp_add(float v) {
    int mv = __builtin_amdgcn_update_dpp(0, __float_as_int(v), CTRL, RM, 0xf, true);
    return v + __int_as_float(mv);
}
__device__ __forceinline__ float wave_sum_hi(float v) {
    v = dpp_add<0xB1, 0xf>(v);   // quad_perm xor1
    v = dpp_add<0x4E, 0xf>(v);   // quad_perm xor2
    v = dpp_add<0x141, 0xf>(v);  // row_half_mirror
    v = dpp_add<0x140, 0xf>(v);  // row_mirror
    v = dpp_add<0x142, 0xa>(v);  // row_bcast15 -> rows 1,3
    v = dpp_add<0x143, 0xc>(v);  // row_bcast31 -> rows 2,3
    return v;
}
__device__ __forceinline__ float bcast63(float v) {
    return __int_as_float(__builtin_amdgcn_readlane(__float_as_int(v), 63));
}

// LDS-only barrier (R14-proven): drains DS, leaves VMEM in flight.
#define LDS_BARRIER() asm volatile("s_waitcnt lgkmcnt(0)\ns_barrier" ::: "memory")

// 256 threads = 4 waves; wave wv owns positions ll = wv*8 .. wv*8+7.
__global__ __launch_bounds__(256, 2)
void dconv1d_kernel(const float* __restrict__ x,
                    const float* __restrict__ w_off,
                    const float* __restrict__ b_off,
                    const float* __restrict__ w_mask,
                    const float* __restrict__ b_mask,
                    float* __restrict__ out) {
    __shared__ float s_tile[TL * C_];          // 32 KB; granule-XOR swizzle
    __shared__ float s_w[384 * WSTR];          // 19.5 KB; weights, stride-13

    const int tid  = threadIdx.x;
    const int lane = tid & 63;
    const int wv   = tid >> 6;          // wave 0..3
    const int l0   = blockIdx.x * TL;
    const int b    = blockIdx.y;
    const float* __restrict__ xb = x + (size_t)b * L_ * C_;

    const float bo0 = b_off[0],  bo1 = b_off[1],  bo2 = b_off[2];
    const float bm0 = b_mask[0], bm1 = b_mask[1], bm2 = b_mask[2];

    const int c4 = lane << 2;           // lane's 4 channels
    const int lb = l0 + wv * 8;         // wave's first position

    // ---- stage all 6x768 weights into LDS once (stride-13 tasks) ----
    #pragma unroll
    for (int task = tid; task < 384; task += 256) {
        const int o  = task >> 6;
        const int ln = task & 63;
        const float* src = ((o < 3) ? (w_off + o * (C_ * 3))
                                    : (w_mask + (o - 3) * (C_ * 3))) + ln * 12;
        const float4 q0 = *reinterpret_cast<const float4*>(src);
        const float4 q1 = *reinterpret_cast<const float4*>(src + 4);
        const float4 q2 = *reinterpret_cast<const float4*>(src + 8);
        float* dst = &s_w[task * WSTR];
        *reinterpret_cast<float4*>(dst)     = q0;
        *reinterpret_cast<float4*>(dst + 4) = q1;
        *reinterpret_cast<float4*>(dst + 8) = q2;
    }

    // ---- 10 rows (lb-1 .. lb+8) loaded ONCE: cover all 8 positions x 3 taps
    float4 xrow[10];
    #pragma unroll
    for (int rr = 0; rr < 10; ++rr) {
        const int row = lb - 1 + rr;
        if (row >= 0 && row < L_)
            xrow[rr] = *reinterpret_cast<const float4*>(
                xb + (size_t)row * C_ + c4);
        else
            xrow[rr] = make_float4(0.f, 0.f, 0.f, 0.f);
    }
    LDS_BARRIER();   // weights staged (xrow loads remain in flight; the
                     // compiler waits them before first use automatically)

    // ---- phase 1: 6 outputs; weights from LDS; 8 indep acc+DPP chains/o ----
    float sums[8][6];                   // wave-uniform after bcast63 (SGPRs)
    #pragma unroll
    for (int o = 0; o < 6; ++o) {
        const float* wbase = &s_w[(o * 64 + lane) * WSTR];
        const float4 w0 = *reinterpret_cast<const float4*>(wbase);
        const float4 w1 = *reinterpret_cast<const float4*>(wbase + 4);
        const float4 w2 = *reinterpret_cast<const float4*>(wbase + 8);
        float acc[8] = {0.f,0.f,0.f,0.f,0.f,0.f,0.f,0.f};
        #pragma unroll
        for (int rr = 0; rr < 10; ++rr) {
            #pragma unroll
            for (int tt = 0; tt < 3; ++tt) {
                const int i = rr - tt;             // compile-time per (rr,tt)
                if (i >= 0 && i < 8) {
                    const float wt0 = (tt==0)?w0.x:((tt==1)?w0.y:w0.z);
                    const float wt1 = (tt==0)?w0.w:((tt==1)?w1.x:w1.y);
                    const float wt2 = (tt==0)?w1.z:((tt==1)?w1.w:w2.x);
                    const float wt3 = (tt==0)?w2.y:((tt==1)?w2.z:w2.w);
                    acc[i] += xrow[rr].x * wt0 + xrow[rr].y * wt1
                            + xrow[rr].z * wt2 + xrow[rr].w * wt3;
                }
            }
        }
        #pragma unroll
        for (int i = 0; i < 8; ++i)
            sums[i][o] = bcast63(wave_sum_hi(acc[i]));
    }

    // ---- phase 2: sampling; gathers global (L1-hot rows); tile store ----
    #pragma unroll
    for (int i = 0; i < 8; ++i) {
        const int ll = wv * 8 + i;
        const int l  = l0 + ll;
        float4 v = make_float4(0.f, 0.f, 0.f, 0.f);
        #pragma unroll
        for (int k = 0; k < 3; ++k) {
            const float bo = (k == 0) ? bo0 : ((k == 1) ? bo1 : bo2);
            const float bm = (k == 0) ? bm0 : ((k == 1) ? bm1 : bm2);
            const float off = sums[i][k] + bo;
            const float pos = fminf(fmaxf((float)l + off, 0.0f), (float)(L_ - 1));
            const float flf = floorf(pos);
            const int   fl  = (int)flf;
            const int   ce  = min(fl + 1, L_ - 1);
            const float a   = pos - flf;
            const float m   = 1.0f / (1.0f + __expf(-(sums[i][k + 3] + bm)));
            const float wf  = m * (1.0f - a);
            const float wc  = m * a;
            const float4 xf = *reinterpret_cast<const float4*>(
                xb + (size_t)fl * C_ + c4);
            const float4 xc = *reinterpret_cast<const float4*>(
                xb + (size_t)ce * C_ + c4);
            v.x += wf * xf.x + wc * xc.x;
            v.y += wf * xf.y + wc * xc.y;
            v.z += wf * xf.z + wc * xc.z;
            v.w += wf * xf.w + wc * xc.w;
        }
        const int gr = lane ^ (ll & 15);           // 16B-granule swizzle
        *reinterpret_cast<float4*>(&s_tile[ll * C_ + (gr << 2)]) = v;
    }
    LDS_BARRIER();

    // ---- phase 3: transpose write-out, full 128B lines along l ----
    {
        const int lw = tid & 31;
        const int q0 = tid >> 5;            // 0..7
        #pragma unroll
        for (int s = 0; s < 8; ++s) {
            const int q  = q0 + (s << 3);   // 0..63 (channels 4q..4q+3)
            const int gr = q ^ (lw & 15);
            const float4 v = *reinterpret_cast<const float4*>(
                &s_tile[lw * C_ + (gr << 2)]);
            const size_t ob = ((size_t)b * C_ + (q << 2)) * L_ + l0 + lw;
            out[ob]          = v.x;
            out[ob + L_]     = v.y;
            out[ob + 2 * L_] = v.z;
            out[ob + 3 * L_] = v.w;
        }
    }
}

extern "C" void kernel_launch(void* const* d_in, const int* in_sizes, int n_in,
                              void* d_out, int out_size, void* d_ws, size_t ws_size,
                              hipStream_t stream) {
    const float* x      = (const float*)d_in[0];
    const float* w_off  = (const float*)d_in[1];
    const float* b_off  = (const float*)d_in[2];
    const float* w_mask = (const float*)d_in[3];
    const float* b_mask = (const float*)d_in[4];
    float* out = (float*)d_out;

    dim3 grid(L_ / TL, B_);
    dconv1d_kernel<<<grid, 256, 0, stream>>>(x, w_off, b_off, w_mask, b_mask, out);
}

// Round 20
// 27.600 us; speedup vs baseline: 1.1069x; 1.1069x over previous
//
#include <hip/hip_runtime.h>
#include <math.h>

#define B_  8
#define L_  4096
#define C_  256
#define TL  32

// ---- DPP wave-sum on the VALU pipe (verified R7/R9/R11) ----
template<int CTRL, int RM>
__device__ __forceinline__ float dpp_add(float v) {
    int mv = __builtin_amdgcn_update_dpp(0, __float_as_int(v), CTRL, RM, 0xf, true);
    return v + __int_as_float(mv);
}
__device__ __forceinline__ float wave_sum_hi(float v) {
    v = dpp_add<0xB1, 0xf>(v);   // quad_perm xor1
    v = dpp_add<0x4E, 0xf>(v);   // quad_perm xor2
    v = dpp_add<0x141, 0xf>(v);  // row_half_mirror
    v = dpp_add<0x140, 0xf>(v);  // row_mirror
    v = dpp_add<0x142, 0xa>(v);  // row_bcast15 -> rows 1,3
    v = dpp_add<0x143, 0xc>(v);  // row_bcast31 -> rows 2,3
    return v;
}
__device__ __forceinline__ float bcast63(float v) {
    return __int_as_float(__builtin_amdgcn_readlane(__float_as_int(v), 63));
}

// 512 threads = 8 waves; wave wv owns positions ll = wv*4 .. wv*4+3.
// XCD-batch binding: 1D grid, b = wgid % 8. Consecutive workgroup IDs
// round-robin across the 8 XCDs, so each XCD sees ONE batch -> its 4MB L2
// caches exactly that batch's x (conv rows + all gather re-reads hit L2
// instead of thrashing across all 8 batches' 33.5MB).
__global__ __launch_bounds__(512, 4)
void dconv1d_kernel(const float* __restrict__ x,
                    const float* __restrict__ w_off,
                    const float* __restrict__ b_off,
                    const float* __restrict__ w_mask,
                    const float* __restrict__ b_mask,
                    float* __restrict__ out) {
    __shared__ float s_tile[TL * C_];   // 32 KB; XOR-granule swizzle (0 conflicts)

    const int tid  = threadIdx.x;
    const int lane = tid & 63;
    const int wv   = tid >> 6;          // wave 0..7
    const int wgid = blockIdx.x;
    const int b    = wgid & 7;          // batch == XCD (round-robin dispatch)
    const int l0   = (wgid >> 3) * TL;  // l-tile
    const float* __restrict__ xb = x + (size_t)b * L_ * C_;

    const float bo0 = b_off[0],  bo1 = b_off[1],  bo2 = b_off[2];
    const float bm0 = b_mask[0], bm1 = b_mask[1], bm2 = b_mask[2];

    const int c4  = lane << 2;          // lane's 4 channels
    const int lb4 = l0 + wv * 4;        // wave's first position

    // ---- phase 1: 6 x-rows loaded once; 6 conv outputs one at a time ----
    float4 xrow[6];
    #pragma unroll
    for (int rr = 0; rr < 6; ++rr) {
        const int row = lb4 - 1 + rr;
        if (row >= 0 && row < L_)
            xrow[rr] = *reinterpret_cast<const float4*>(
                xb + (size_t)row * C_ + c4);
        else
            xrow[rr] = make_float4(0.f, 0.f, 0.f, 0.f);
    }

    float sums[4][6];   // wave-uniform after bcast63 (SGPRs)
    #pragma unroll
    for (int o = 0; o < 6; ++o) {
        const float* ws = (o < 3) ? (w_off + o * (C_ * 3))
                                  : (w_mask + (o - 3) * (C_ * 3));
        const float4* wp = reinterpret_cast<const float4*>(ws + lane * 12);
        const float4 w0 = wp[0], w1 = wp[1], w2 = wp[2];
        float acc[4] = {0.f, 0.f, 0.f, 0.f};
        #pragma unroll
        for (int rr = 0; rr < 6; ++rr) {
            #pragma unroll
            for (int tt = 0; tt < 3; ++tt) {
                const int i = rr - tt;             // compile-time per (rr,tt)
                if (i >= 0 && i < 4) {
                    const float wt0 = (tt==0)?w0.x:((tt==1)?w0.y:w0.z);
                    const float wt1 = (tt==0)?w0.w:((tt==1)?w1.x:w1.y);
                    const float wt2 = (tt==0)?w1.z:((tt==1)?w1.w:w2.x);
                    const float wt3 = (tt==0)?w2.y:((tt==1)?w2.z:w2.w);
                    acc[i] += xrow[rr].x * wt0 + xrow[rr].y * wt1
                            + xrow[rr].z * wt2 + xrow[rr].w * wt3;
                }
            }
        }
        // 4 independent DPP chains -> SGPR broadcast
        #pragma unroll
        for (int i = 0; i < 4; ++i)
            sums[i][o] = bcast63(wave_sum_hi(acc[i]));
    }

    // ---- phase 2: wave-local sampling of its 4 positions (zero DS reads) ----
    #pragma unroll
    for (int i = 0; i < 4; ++i) {
        const int ll = wv * 4 + i;
        const int l  = l0 + ll;
        float4 v = make_float4(0.f, 0.f, 0.f, 0.f);
        #pragma unroll
        for (int k = 0; k < 3; ++k) {
            const float bo = (k == 0) ? bo0 : ((k == 1) ? bo1 : bo2);
            const float bm = (k == 0) ? bm0 : ((k == 1) ? bm1 : bm2);
            const float off = sums[i][k] + bo;
            const float pos = fminf(fmaxf((float)l + off, 0.0f), (float)(L_ - 1));
            const float flf = floorf(pos);
            const int   fl  = (int)flf;
            const int   ce  = min(fl + 1, L_ - 1);
            const float a   = pos - flf;
            const float m   = 1.0f / (1.0f + __expf(-(sums[i][k + 3] + bm)));
            const float wf  = m * (1.0f - a);
            const float wc  = m * a;
            const float4 xf = *reinterpret_cast<const float4*>(
                xb + (size_t)fl * C_ + c4);
            const float4 xc = *reinterpret_cast<const float4*>(
                xb + (size_t)ce * C_ + c4);
            v.x += wf * xf.x + wc * xc.x;
            v.y += wf * xf.y + wc * xc.y;
            v.z += wf * xf.z + wc * xc.z;
            v.w += wf * xf.w + wc * xc.w;
        }
        const int gr = lane ^ (ll & 15);   // 16B-granule swizzle
        *reinterpret_cast<float4*>(&s_tile[ll * C_ + (gr << 2)]) = v;
    }
    __syncthreads();

    // ---- phase 3: transpose write-out, full 128B lines along l ----
    {
        const int lw = tid & 31;
        const int q0 = tid >> 5;           // 0..15
        #pragma unroll
        for (int s = 0; s < 4; ++s) {
            const int q  = q0 + (s << 4);  // 0..63 (channels 4q..4q+3)
            const int gr = q ^ (lw & 15);
            const float4 v = *reinterpret_cast<const float4*>(
                &s_tile[lw * C_ + (gr << 2)]);
            const size_t ob = ((size_t)b * C_ + (q << 2)) * L_ + l0 + lw;
            out[ob]          = v.x;
            out[ob + L_]     = v.y;
            out[ob + 2 * L_] = v.z;
            out[ob + 3 * L_] = v.w;
        }
    }
}

extern "C" void kernel_launch(void* const* d_in, const int* in_sizes, int n_in,
                              void* d_out, int out_size, void* d_ws, size_t ws_size,
                              hipStream_t stream) {
    const float* x      = (const float*)d_in[0];
    const float* w_off  = (const float*)d_in[1];
    const float* b_off  = (const float*)d_in[2];
    const float* w_mask = (const float*)d_in[3];
    const float* b_mask = (const float*)d_in[4];
    float* out = (float*)d_out;

    dconv1d_kernel<<<(L_ / TL) * B_, 512, 0, stream>>>(
        x, w_off, b_off, w_mask, b_mask, out);
}